// Round 5
// baseline (373.765 us; speedup 1.0000x reference)
//
#include <hip/hip_runtime.h>
#include <hip/hip_bf16.h>

// GraphSAGE backbone: 2x SAGEConv(mean), N=100000, E=1600000, D=128, fp32 in/out.
// CSR build via 2-pass bucket binning, then per layer:
//   agg = mean gather (bf16 rows, fp32 accum);  out = relu(agg@Wl + h@Wr + b)
//   fused bf16 MFMA GEMM with LDS-staged coalesced epilogue.

#define D 128
#define WSTRIDE 136            // 128 + 8 bf16 pad
#define WPANEL (D * WSTRIDE)   // shorts per weight panel
#define GCAP 12288             // per-bucket capacity (mean ~8166, +45 sigma)

typedef __attribute__((ext_vector_type(8))) short short8v;
typedef __attribute__((ext_vector_type(4))) float f32x4;

__device__ inline unsigned short f2bf(float f) {   // fp32 -> bf16 RNE
  unsigned u = __float_as_uint(f);
  return (unsigned short)((u + 0x7FFFu + ((u >> 16) & 1u)) >> 16);
}
__device__ inline unsigned pack2(float lo, float hi) {
  return (unsigned)f2bf(lo) | ((unsigned)f2bf(hi) << 16);
}

// ---- pass A: bin edges by dst>>9 into gbuf[b*GCAP + cursor] ---------------

__global__ __launch_bounds__(256) void k_bin(const int* __restrict__ ei, int E,
                                             int* __restrict__ gcur,
                                             int* __restrict__ gbuf) {
  __shared__ int hcnt[256], hbase[256], hfill[256];
  int tid = threadIdx.x;
  hcnt[tid] = 0;
  __syncthreads();
  int ent[8], bk[8];
#pragma unroll
  for (int it = 0; it < 8; ++it) {
    int e = blockIdx.x * 2048 + it * 256 + tid;
    if (e < E) {
      int s = ei[e], d = ei[E + e];
      bk[it] = d >> 9;
      ent[it] = (s << 9) | (d & 511);
      atomicAdd(&hcnt[bk[it]], 1);
    } else bk[it] = -1;
  }
  __syncthreads();
  int c = hcnt[tid];
  hbase[tid] = c ? atomicAdd(&gcur[tid], c) : 0;
  hfill[tid] = 0;
  __syncthreads();
#pragma unroll
  for (int it = 0; it < 8; ++it) {
    if (bk[it] >= 0) {
      int slot = atomicAdd(&hfill[bk[it]], 1);
      gbuf[(size_t)bk[it] * GCAP + hbase[bk[it]] + slot] = ent[it];
    }
  }
}

// ---- pass B1: per-bucket degree histogram -> cnt (coalesced) ---------------

__global__ __launch_bounds__(256) void k_hist(const int* __restrict__ gcur,
                                              const int* __restrict__ gbuf,
                                              int* __restrict__ cnt, int n) {
  __shared__ int hc[512];
  int b = blockIdx.x, tid = threadIdx.x;
  hc[tid] = 0; hc[tid + 256] = 0;
  __syncthreads();
  int m = gcur[b];
  for (int i = tid; i < m; i += 256)
    atomicAdd(&hc[gbuf[(size_t)b * GCAP + i] & 511], 1);
  __syncthreads();
#pragma unroll
  for (int k = 0; k < 2; ++k) {
    int i = k * 256 + tid, node = b * 512 + i;
    if (node < n) cnt[node] = hc[i];
  }
}

// ---- hierarchical exclusive scan: cnt -> rowptr, plus inv_denom ------------

__global__ __launch_bounds__(1024) void k_scan1(const int* __restrict__ cnt, int n,
                                                int* __restrict__ rowptr,
                                                float* __restrict__ inv_denom,
                                                int* __restrict__ bsum) {
  __shared__ int wsum[16];
  int tid = threadIdx.x, lane = tid & 63, wid = tid >> 6;
  int i = blockIdx.x * 1024 + tid;
  int v = (i < n) ? cnt[i] : 0;
  int x = v;
#pragma unroll
  for (int off = 1; off < 64; off <<= 1) {
    int t = __shfl_up(x, (unsigned)off);
    if (lane >= off) x += t;
  }
  if (lane == 63) wsum[wid] = x;
  __syncthreads();
  if (tid < 16) {
    int w = wsum[tid], y = w;
#pragma unroll
    for (int off = 1; off < 16; off <<= 1) {
      int t = __shfl_up(y, (unsigned)off);
      if (tid >= off) y += t;
    }
    wsum[tid] = y - w;   // exclusive
  }
  __syncthreads();
  if (i < n) {
    rowptr[i] = wsum[wid] + x - v;
    inv_denom[i] = 1.0f / (float)((v > 1) ? v : 1);
  }
  if (tid == 1023) bsum[blockIdx.x] = wsum[15] + x;
}

__global__ __launch_bounds__(64) void k_scan2(int* __restrict__ bsum, int nb,
                                              int* __restrict__ rowptr, int n) {
  int lane = threadIdx.x;
  int v0 = (lane < nb) ? bsum[lane] : 0;
  int v1 = (64 + lane < nb) ? bsum[64 + lane] : 0;
  int x = v0;
#pragma unroll
  for (int off = 1; off < 64; off <<= 1) {
    int t = __shfl_up(x, (unsigned)off);
    if (lane >= off) x += t;
  }
  int tot0 = __shfl(x, 63);
  int y = v1;
#pragma unroll
  for (int off = 1; off < 64; off <<= 1) {
    int t = __shfl_up(y, (unsigned)off);
    if (lane >= off) y += t;
  }
  if (lane < nb) bsum[lane] = x - v0;
  if (64 + lane < nb) bsum[64 + lane] = tot0 + (y - v1);
  if (lane == 63) rowptr[n] = tot0 + y;
}

__global__ __launch_bounds__(1024) void k_scan3(int* __restrict__ rowptr,
                                                const int* __restrict__ bsum, int n) {
  int i = blockIdx.x * 1024 + threadIdx.x;
  if (i < n) rowptr[i] += bsum[blockIdx.x];
}

// ---- pass B2: place entries into csr (one bucket = one block) --------------

__global__ __launch_bounds__(256) void k_place(const int* __restrict__ gcur,
                                               const int* __restrict__ gbuf,
                                               const int* __restrict__ rowptr,
                                               int* __restrict__ csr, int n) {
  __shared__ int rp[512], hf[512];
  int b = blockIdx.x, tid = threadIdx.x;
#pragma unroll
  for (int k = 0; k < 2; ++k) {
    int i = k * 256 + tid, node = b * 512 + i;
    rp[i] = (node < n) ? rowptr[node] : 0;
    hf[i] = 0;
  }
  __syncthreads();
  int m = gcur[b];
  for (int i = tid; i < m; i += 256) {
    int ent = gbuf[(size_t)b * GCAP + i];
    int d = ent & 511, s = ent >> 9;
    csr[rp[d] + atomicAdd(&hf[d], 1)] = s;
  }
}

// ---- fp32 -> bf16 row conversion ------------------------------------------

__global__ __launch_bounds__(256) void k_tobf16(const float* __restrict__ in,
                                                short* __restrict__ ob, long long ng) {
  long long i = (long long)blockIdx.x * 256 + threadIdx.x;   // groups of 8 floats
  if (i >= ng) return;
  const float4* p = (const float4*)in + i * 2;
  float4 a = p[0], b = p[1];
  uint4 o;
  o.x = pack2(a.x, a.y); o.y = pack2(a.z, a.w);
  o.z = pack2(b.x, b.y); o.w = pack2(b.z, b.w);
  ((uint4*)ob)[i] = o;
}

// ---- weight prep: fp32 W[k][c] -> bf16 transposed WT[c][k] ----------------

__global__ __launch_bounds__(256) void k_wprep(const float* __restrict__ W0,
                                               const float* __restrict__ W1,
                                               const float* __restrict__ W2,
                                               const float* __restrict__ W3,
                                               short* __restrict__ WT) {
  const float* W = (blockIdx.y == 0) ? W0 : (blockIdx.y == 1) ? W1
                 : (blockIdx.y == 2) ? W2 : W3;
  short* o = WT + (size_t)blockIdx.y * WPANEL;
  int i = blockIdx.x * 256 + threadIdx.x;
  if (i < D * D) {
    int k = i >> 7, c = i & 127;
    o[c * WSTRIDE + k] = (short)f2bf(W[i]);
  }
}

// ---- bf16 mean aggregation: wave/node, 16-lane quarters --------------------

__global__ __launch_bounds__(256) void k_agg_bf(const short* __restrict__ hb,
                                                const int* __restrict__ rowptr,
                                                const int* __restrict__ csr,
                                                const float* __restrict__ inv_denom,
                                                short* __restrict__ agg, int n) {
  int gw = (int)((blockIdx.x * 256u + threadIdx.x) >> 6);
  if (gw >= n) return;
  int lane = threadIdx.x & 63;
  int q = lane >> 4, s16 = lane & 15;
  int beg = __builtin_amdgcn_readfirstlane(rowptr[gw]);
  int end = __builtin_amdgcn_readfirstlane(rowptr[gw + 1]);
  float acc[8];
#pragma unroll
  for (int k = 0; k < 8; ++k) acc[k] = 0.f;
  int e = beg + q;
  for (; e + 4 < end; e += 8) {   // 2 edges per quarter in flight
    int s0 = csr[e], s1 = csr[e + 4];
    uint4 v0 = ((const uint4*)(hb + (size_t)s0 * D))[s16];
    uint4 v1 = ((const uint4*)(hb + (size_t)s1 * D))[s16];
    acc[0] += __uint_as_float(v0.x << 16); acc[1] += __uint_as_float(v0.x & 0xffff0000u);
    acc[2] += __uint_as_float(v0.y << 16); acc[3] += __uint_as_float(v0.y & 0xffff0000u);
    acc[4] += __uint_as_float(v0.z << 16); acc[5] += __uint_as_float(v0.z & 0xffff0000u);
    acc[6] += __uint_as_float(v0.w << 16); acc[7] += __uint_as_float(v0.w & 0xffff0000u);
    acc[0] += __uint_as_float(v1.x << 16); acc[1] += __uint_as_float(v1.x & 0xffff0000u);
    acc[2] += __uint_as_float(v1.y << 16); acc[3] += __uint_as_float(v1.y & 0xffff0000u);
    acc[4] += __uint_as_float(v1.z << 16); acc[5] += __uint_as_float(v1.z & 0xffff0000u);
    acc[6] += __uint_as_float(v1.w << 16); acc[7] += __uint_as_float(v1.w & 0xffff0000u);
  }
  if (e < end) {
    int s0 = csr[e];
    uint4 v0 = ((const uint4*)(hb + (size_t)s0 * D))[s16];
    acc[0] += __uint_as_float(v0.x << 16); acc[1] += __uint_as_float(v0.x & 0xffff0000u);
    acc[2] += __uint_as_float(v0.y << 16); acc[3] += __uint_as_float(v0.y & 0xffff0000u);
    acc[4] += __uint_as_float(v0.z << 16); acc[5] += __uint_as_float(v0.z & 0xffff0000u);
    acc[6] += __uint_as_float(v0.w << 16); acc[7] += __uint_as_float(v0.w & 0xffff0000u);
  }
#pragma unroll
  for (int k = 0; k < 8; ++k) {
    acc[k] += __shfl_xor(acc[k], 16);
    acc[k] += __shfl_xor(acc[k], 32);
  }
  if (q == 0) {
    float iv = inv_denom[gw];
    uint4 o;
    o.x = pack2(acc[0] * iv, acc[1] * iv);
    o.y = pack2(acc[2] * iv, acc[3] * iv);
    o.z = pack2(acc[4] * iv, acc[5] * iv);
    o.w = pack2(acc[6] * iv, acc[7] * iv);
    ((uint4*)(agg + (size_t)gw * D))[s16] = o;
  }
}

// ---- fused layer GEMM (bf16 operands): out = relu(A@Wl + H@Wr + b) ---------
// OUTF=0: bf16 out; OUTF=1: fp32 out. Epilogue staged through per-wave LDS
// (padded stride) -> fully coalesced global stores (no partial-line writes).

template <int OUTF>
__global__ __launch_bounds__(512) void k_fgemm_bf(const short* __restrict__ A,
                                                  const short* __restrict__ H,
                                                  const short* __restrict__ WTl,
                                                  const short* __restrict__ WTr,
                                                  const float* __restrict__ bias,
                                                  void* __restrict__ outv, int n) {
  __shared__ short wl[WPANEL];
  __shared__ short wr[WPANEL];
  constexpr int SSTR = OUTF ? 132 : 136;          // elems per staged row (pad)
  constexpr int SBYTES = 8 * 16 * SSTR * (OUTF ? 4 : 2);
  __shared__ int4 stageraw[SBYTES / 16];

  int tid = threadIdx.x;
  for (int i = tid; i < WPANEL / 8; i += 512) {
    ((int4*)wl)[i] = ((const int4*)WTl)[i];
    ((int4*)wr)[i] = ((const int4*)WTr)[i];
  }
  __syncthreads();

  int lane = tid & 63, wid = tid >> 6;
  int c = lane & 15, g = lane >> 4;
  float bv[8];
#pragma unroll
  for (int cc = 0; cc < 8; ++cc) bv[cc] = bias[cc * 16 + c];

  int srow = lane >> 2, sch = lane & 3;           // epilogue readback mapping

  int ntile = (n + 15) >> 4;
  for (int tile = blockIdx.x * 8 + wid; tile < ntile; tile += gridDim.x * 8) {
    int r0 = tile * 16;
    int row = r0 + c;
    bool rok = row < n;
    f32x4 acc[8];
#pragma unroll
    for (int cc = 0; cc < 8; ++cc) acc[cc] = (f32x4){0.f, 0.f, 0.f, 0.f};

#pragma unroll
    for (int t = 0; t < 4; ++t) {
      short8v af = (short8v){0,0,0,0,0,0,0,0};
      short8v hf = (short8v){0,0,0,0,0,0,0,0};
      if (rok) {
        af = *(const short8v*)(A + (size_t)row * D + t * 32 + g * 8);
        hf = *(const short8v*)(H + (size_t)row * D + t * 32 + g * 8);
      }
      int kb = t * 32 + g * 8;
#pragma unroll
      for (int cc = 0; cc < 8; ++cc) {
        short8v bl = *(const short8v*)&wl[(cc * 16 + c) * WSTRIDE + kb];
        acc[cc] = __builtin_amdgcn_mfma_f32_16x16x32_bf16(af, bl, acc[cc], 0, 0, 0);
        short8v br = *(const short8v*)&wr[(cc * 16 + c) * WSTRIDE + kb];
        acc[cc] = __builtin_amdgcn_mfma_f32_16x16x32_bf16(hf, br, acc[cc], 0, 0, 0);
      }
    }

    if (OUTF) {
      float* st = (float*)stageraw + (size_t)wid * 16 * SSTR;
#pragma unroll
      for (int cc = 0; cc < 8; ++cc)
#pragma unroll
        for (int i = 0; i < 4; ++i) {
          float o = acc[cc][i] + bv[cc];
          st[(g * 4 + i) * SSTR + cc * 16 + c] = o > 0.f ? o : 0.f;
        }
      // wave-private: same-wave LDS RAW ordered by lgkmcnt (compiler)
      if (r0 + srow < n) {
        const float4* src = (const float4*)(st + srow * SSTR + sch * 32);
        float4* dst = (float4*)((float*)outv + (size_t)(r0 + srow) * D + sch * 32);
#pragma unroll
        for (int j = 0; j < 8; ++j) dst[j] = src[j];
      }
    } else {
      short* st = (short*)stageraw + (size_t)wid * 16 * SSTR;
#pragma unroll
      for (int cc = 0; cc < 8; ++cc)
#pragma unroll
        for (int i = 0; i < 4; ++i) {
          float o = acc[cc][i] + bv[cc];
          st[(g * 4 + i) * SSTR + cc * 16 + c] = (short)f2bf(o > 0.f ? o : 0.f);
        }
      if (r0 + srow < n) {
        const int4* src = (const int4*)(st + srow * SSTR + sch * 32);
        int4* dst = (int4*)((short*)outv + (size_t)(r0 + srow) * D + sch * 32);
#pragma unroll
        for (int j = 0; j < 4; ++j) dst[j] = src[j];
      }
    }
  }
}

// ---- fp32 fallback kernels (used only if ws_size is too small) -------------

__global__ __launch_bounds__(256) void k_agg_f32(const float* __restrict__ h,
                                                 const int* __restrict__ rowptr,
                                                 const int* __restrict__ csr,
                                                 const float* __restrict__ inv_denom,
                                                 float* __restrict__ agg, int n) {
  int gw = (int)((blockIdx.x * 256u + threadIdx.x) >> 6);
  if (gw >= n) return;
  int lane = threadIdx.x & 63;
  int half = lane >> 5, sub = lane & 31;
  int beg = __builtin_amdgcn_readfirstlane(rowptr[gw]);
  int end = __builtin_amdgcn_readfirstlane(rowptr[gw + 1]);
  float sx0 = 0.f, sy0 = 0.f, sz0 = 0.f, sw0 = 0.f;
  float sx1 = 0.f, sy1 = 0.f, sz1 = 0.f, sw1 = 0.f;
  int e = beg;
  for (; e + 4 <= end; e += 4) {
    int i0 = csr[e + half];
    int i1 = csr[e + 2 + half];
    float4 v0 = ((const float4*)(h + (size_t)i0 * D))[sub];
    float4 v1 = ((const float4*)(h + (size_t)i1 * D))[sub];
    sx0 += v0.x; sy0 += v0.y; sz0 += v0.z; sw0 += v0.w;
    sx1 += v1.x; sy1 += v1.y; sz1 += v1.z; sw1 += v1.w;
  }
  if (e + 2 <= end) {
    int i0 = csr[e + half];
    float4 v0 = ((const float4*)(h + (size_t)i0 * D))[sub];
    sx0 += v0.x; sy0 += v0.y; sz0 += v0.z; sw0 += v0.w;
    e += 2;
  }
  if (e < end) {
    int i0 = csr[e];
    float4 v0 = ((const float4*)(h + (size_t)i0 * D))[sub];
    if (half == 0) { sx0 += v0.x; sy0 += v0.y; sz0 += v0.z; sw0 += v0.w; }
  }
  float sx = sx0 + sx1, sy = sy0 + sy1, sz = sz0 + sz1, sw = sw0 + sw1;
  sx += __shfl_xor(sx, 32); sy += __shfl_xor(sy, 32);
  sz += __shfl_xor(sz, 32); sw += __shfl_xor(sw, 32);
  if (half == 0) {
    float iv = inv_denom[gw];
    float4 r; r.x = sx * iv; r.y = sy * iv; r.z = sz * iv; r.w = sw * iv;
    ((float4*)(agg + (size_t)gw * D))[sub] = r;
  }
}

__global__ __launch_bounds__(512) void k_fgemm_f32(const float* A, const float* H,
                                                   const short* __restrict__ WTl,
                                                   const short* __restrict__ WTr,
                                                   const float* __restrict__ bias,
                                                   float* out, int n) {
  __shared__ short wl[WPANEL];
  __shared__ short wr[WPANEL];
  int tid = threadIdx.x;
  for (int i = tid; i < WPANEL / 8; i += 512) {
    ((int4*)wl)[i] = ((const int4*)WTl)[i];
    ((int4*)wr)[i] = ((const int4*)WTr)[i];
  }
  __syncthreads();
  int lane = tid & 63, wid = tid >> 6;
  int c = lane & 15, g = lane >> 4;
  float bv[8];
#pragma unroll
  for (int cc = 0; cc < 8; ++cc) bv[cc] = bias[cc * 16 + c];
  int ntile = (n + 15) >> 4;
  for (int tile = blockIdx.x * 8 + wid; tile < ntile; tile += gridDim.x * 8) {
    int r0 = tile * 16;
    int row = r0 + c;
    bool rok = row < n;
    f32x4 acc[8];
#pragma unroll
    for (int cc = 0; cc < 8; ++cc) acc[cc] = (f32x4){0.f, 0.f, 0.f, 0.f};
#pragma unroll
    for (int t = 0; t < 4; ++t) {
      short8v af = (short8v){0,0,0,0,0,0,0,0};
      short8v hf = (short8v){0,0,0,0,0,0,0,0};
      if (rok) {
        const float4* pa = (const float4*)(A + (size_t)row * D + t * 32 + g * 8);
        float4 a0 = pa[0], a1 = pa[1];
        const float4* ph = (const float4*)(H + (size_t)row * D + t * 32 + g * 8);
        float4 h0 = ph[0], h1 = ph[1];
        af[0] = (short)f2bf(a0.x); af[1] = (short)f2bf(a0.y); af[2] = (short)f2bf(a0.z); af[3] = (short)f2bf(a0.w);
        af[4] = (short)f2bf(a1.x); af[5] = (short)f2bf(a1.y); af[6] = (short)f2bf(a1.z); af[7] = (short)f2bf(a1.w);
        hf[0] = (short)f2bf(h0.x); hf[1] = (short)f2bf(h0.y); hf[2] = (short)f2bf(h0.z); hf[3] = (short)f2bf(h0.w);
        hf[4] = (short)f2bf(h1.x); hf[5] = (short)f2bf(h1.y); hf[6] = (short)f2bf(h1.z); hf[7] = (short)f2bf(h1.w);
      }
      int kb = t * 32 + g * 8;
#pragma unroll
      for (int cc = 0; cc < 8; ++cc) {
        short8v bl = *(const short8v*)&wl[(cc * 16 + c) * WSTRIDE + kb];
        acc[cc] = __builtin_amdgcn_mfma_f32_16x16x32_bf16(af, bl, acc[cc], 0, 0, 0);
        short8v br = *(const short8v*)&wr[(cc * 16 + c) * WSTRIDE + kb];
        acc[cc] = __builtin_amdgcn_mfma_f32_16x16x32_bf16(hf, br, acc[cc], 0, 0, 0);
      }
    }
#pragma unroll
    for (int cc = 0; cc < 8; ++cc) {
#pragma unroll
      for (int i = 0; i < 4; ++i) {
        int rr = r0 + g * 4 + i;
        if (rr < n) {
          float o = acc[cc][i] + bv[cc];
          out[(size_t)rr * D + cc * 16 + c] = o > 0.f ? o : 0.f;
        }
      }
    }
  }
}

// ---- launch ----------------------------------------------------------------

extern "C" void kernel_launch(void* const* d_in, const int* in_sizes, int n_in,
                              void* d_out, int out_size, void* d_ws, size_t ws_size,
                              hipStream_t stream) {
  const float* x   = (const float*)d_in[0];
  const int*   ei  = (const int*)d_in[1];
  const float* Wl0 = (const float*)d_in[2];
  const float* Wr0 = (const float*)d_in[3];
  const float* b0  = (const float*)d_in[4];
  const float* Wl1 = (const float*)d_in[5];
  const float* Wr1 = (const float*)d_in[6];
  const float* b1  = (const float*)d_in[7];
  const int N = in_sizes[0] / D;
  const int E = in_sizes[1] / 2;
  float* out = (float*)d_out;

  size_t NP = ((size_t)N + 64) & ~(size_t)63;
  size_t EP = ((size_t)E + 63) & ~(size_t)63;
  const int NBUCK = (N + 511) >> 9;

  int* W = (int*)d_ws;
  size_t off = 0;
  int*   rowptr = W + off; off += NP;
  int*   cnt    = W + off; off += NP;
  float* inv    = (float*)(W + off); off += NP;
  int*   bsum   = W + off; off += 1024;
  int*   gcur   = W + off; off += 256;
  int*   csr    = W + off; off += EP;
  short* wt     = (short*)(W + off); off += (size_t)4 * WPANEL / 2;
  size_t base = off;
  short* aggb = (short*)(W + off); off += NP * 64;
  short* xb   = (short*)(W + off); off += NP * 64;
  short* h1b  = (short*)(W + off); off += NP * 64;
  size_t need_new = off * 4;
  float* aggf = (float*)(W + base);                 // fallback fp32 agg buffer
  bool use_bf = ws_size >= need_new;
  int* gbuf = use_bf ? (int*)xb : (int*)aggf;       // overlay: consumed pre-agg

  hipMemsetAsync(gcur, 0, 256 * sizeof(int), stream);

  int NB = (N + 1023) / 1024;
  k_bin<<<(E + 2047) / 2048, 256, 0, stream>>>(ei, E, gcur, gbuf);
  k_hist<<<NBUCK, 256, 0, stream>>>(gcur, gbuf, cnt, N);
  k_scan1<<<NB, 1024, 0, stream>>>(cnt, N, rowptr, inv, bsum);
  k_scan2<<<1, 64, 0, stream>>>(bsum, NB, rowptr, N);
  k_scan3<<<NB, 1024, 0, stream>>>(rowptr, bsum, N);
  k_place<<<NBUCK, 256, 0, stream>>>(gcur, gbuf, rowptr, csr, N);

  dim3 wgrid((D * D + 255) / 256, 4);
  k_wprep<<<wgrid, 256, 0, stream>>>(Wl0, Wr0, Wl1, Wr1, wt);

  int agrid = (N + 3) / 4;
  int ggrid = ((N + 15) / 16 + 7) / 8;   // ~1 tile per wave

  if (use_bf) {
    long long ng = (long long)N * (D / 8);
    k_tobf16<<<(int)((ng + 255) / 256), 256, 0, stream>>>(x, xb, ng);
    // layer 0
    k_agg_bf<<<agrid, 256, 0, stream>>>(xb, rowptr, csr, inv, aggb, N);
    k_fgemm_bf<0><<<ggrid, 512, 0, stream>>>(aggb, xb, wt, wt + WPANEL, b0, h1b, N);
    // layer 1
    k_agg_bf<<<agrid, 256, 0, stream>>>(h1b, rowptr, csr, inv, aggb, N);
    k_fgemm_bf<1><<<ggrid, 512, 0, stream>>>(aggb, h1b, wt + 2 * WPANEL, wt + 3 * WPANEL, b1, out, N);
  } else {
    // fp32 fallback (proven footprint)
    k_agg_f32<<<agrid, 256, 0, stream>>>(x, rowptr, csr, inv, aggf, N);
    k_fgemm_f32<<<512, 512, 0, stream>>>(aggf, x, wt, wt + WPANEL, b0, out, N);
    k_agg_f32<<<agrid, 256, 0, stream>>>(out, rowptr, csr, inv, aggf, N);
    k_fgemm_f32<<<512, 512, 0, stream>>>(aggf, out, wt + 2 * WPANEL, wt + 3 * WPANEL, b1, out, N);
  }
}

// Round 6
// 323.615 us; speedup vs baseline: 1.1550x; 1.1550x over previous
//
#include <hip/hip_runtime.h>
#include <hip/hip_bf16.h>

// GraphSAGE backbone: 2x SAGEConv(mean), N=100000, E=1600000, D=128, fp32 in/out.
// CSR build via 2-pass bucket binning, then per layer:
//   agg = mean gather (bf16 rows, fp32 accum);  out = relu(agg@Wl + h@Wr + b)
//   fused bf16 MFMA GEMM; epilogue staged per-wave through a small LDS slice
//   with per-INSTRUCTION contiguous readback (full-line global writes).

#define D 128
#define WSTRIDE 136            // 128 + 8 bf16 pad
#define WPANEL (D * WSTRIDE)   // shorts per weight panel
#define GCAP 12288             // per-bucket capacity (mean ~8166)

typedef __attribute__((ext_vector_type(8))) short short8v;
typedef __attribute__((ext_vector_type(4))) float f32x4;

__device__ inline unsigned short f2bf(float f) {   // fp32 -> bf16 RNE
  unsigned u = __float_as_uint(f);
  return (unsigned short)((u + 0x7FFFu + ((u >> 16) & 1u)) >> 16);
}
__device__ inline unsigned pack2(float lo, float hi) {
  return (unsigned)f2bf(lo) | ((unsigned)f2bf(hi) << 16);
}

// ---- pass A: bin edges by dst>>9 into gbuf[b*GCAP + cursor] ---------------

__global__ __launch_bounds__(256) void k_bin(const int* __restrict__ ei, int E,
                                             int* __restrict__ gcur,
                                             int* __restrict__ gbuf) {
  __shared__ int hcnt[256], hbase[256], hfill[256];
  int tid = threadIdx.x;
  hcnt[tid] = 0;
  __syncthreads();
  int ent[8], bk[8];
#pragma unroll
  for (int it = 0; it < 8; ++it) {
    int e = blockIdx.x * 2048 + it * 256 + tid;
    if (e < E) {
      int s = ei[e], d = ei[E + e];
      bk[it] = d >> 9;
      ent[it] = (s << 9) | (d & 511);
      atomicAdd(&hcnt[bk[it]], 1);
    } else bk[it] = -1;
  }
  __syncthreads();
  int c = hcnt[tid];
  hbase[tid] = c ? atomicAdd(&gcur[tid], c) : 0;
  hfill[tid] = 0;
  __syncthreads();
#pragma unroll
  for (int it = 0; it < 8; ++it) {
    if (bk[it] >= 0) {
      int slot = atomicAdd(&hfill[bk[it]], 1);
      gbuf[(size_t)bk[it] * GCAP + hbase[bk[it]] + slot] = ent[it];
    }
  }
}

// ---- pass B1: per-bucket degree histogram -> cnt (coalesced) ---------------

__global__ __launch_bounds__(256) void k_hist(const int* __restrict__ gcur,
                                              const int* __restrict__ gbuf,
                                              int* __restrict__ cnt, int n) {
  __shared__ int hc[512];
  int b = blockIdx.x, tid = threadIdx.x;
  hc[tid] = 0; hc[tid + 256] = 0;
  __syncthreads();
  int m = gcur[b];
  for (int i = tid; i < m; i += 256)
    atomicAdd(&hc[gbuf[(size_t)b * GCAP + i] & 511], 1);
  __syncthreads();
#pragma unroll
  for (int k = 0; k < 2; ++k) {
    int i = k * 256 + tid, node = b * 512 + i;
    if (node < n) cnt[node] = hc[i];
  }
}

// ---- hierarchical exclusive scan: cnt -> rowptr, plus inv_denom ------------

__global__ __launch_bounds__(1024) void k_scan1(const int* __restrict__ cnt, int n,
                                                int* __restrict__ rowptr,
                                                float* __restrict__ inv_denom,
                                                int* __restrict__ bsum) {
  __shared__ int wsum[16];
  int tid = threadIdx.x, lane = tid & 63, wid = tid >> 6;
  int i = blockIdx.x * 1024 + tid;
  int v = (i < n) ? cnt[i] : 0;
  int x = v;
#pragma unroll
  for (int off = 1; off < 64; off <<= 1) {
    int t = __shfl_up(x, (unsigned)off);
    if (lane >= off) x += t;
  }
  if (lane == 63) wsum[wid] = x;
  __syncthreads();
  if (tid < 16) {
    int w = wsum[tid], y = w;
#pragma unroll
    for (int off = 1; off < 16; off <<= 1) {
      int t = __shfl_up(y, (unsigned)off);
      if (tid >= off) y += t;
    }
    wsum[tid] = y - w;   // exclusive
  }
  __syncthreads();
  if (i < n) {
    rowptr[i] = wsum[wid] + x - v;
    inv_denom[i] = 1.0f / (float)((v > 1) ? v : 1);
  }
  if (tid == 1023) bsum[blockIdx.x] = wsum[15] + x;
}

__global__ __launch_bounds__(64) void k_scan2(int* __restrict__ bsum, int nb,
                                              int* __restrict__ rowptr, int n) {
  int lane = threadIdx.x;
  int v0 = (lane < nb) ? bsum[lane] : 0;
  int v1 = (64 + lane < nb) ? bsum[64 + lane] : 0;
  int x = v0;
#pragma unroll
  for (int off = 1; off < 64; off <<= 1) {
    int t = __shfl_up(x, (unsigned)off);
    if (lane >= off) x += t;
  }
  int tot0 = __shfl(x, 63);
  int y = v1;
#pragma unroll
  for (int off = 1; off < 64; off <<= 1) {
    int t = __shfl_up(y, (unsigned)off);
    if (lane >= off) y += t;
  }
  if (lane < nb) bsum[lane] = x - v0;
  if (64 + lane < nb) bsum[64 + lane] = tot0 + (y - v1);
  if (lane == 63) rowptr[n] = tot0 + y;
}

__global__ __launch_bounds__(1024) void k_scan3(int* __restrict__ rowptr,
                                                const int* __restrict__ bsum, int n) {
  int i = blockIdx.x * 1024 + threadIdx.x;
  if (i < n) rowptr[i] += bsum[blockIdx.x];
}

// ---- pass B2: place entries into csr (one bucket = one block) --------------

__global__ __launch_bounds__(256) void k_place(const int* __restrict__ gcur,
                                               const int* __restrict__ gbuf,
                                               const int* __restrict__ rowptr,
                                               int* __restrict__ csr, int n) {
  __shared__ int rp[512], hf[512];
  int b = blockIdx.x, tid = threadIdx.x;
#pragma unroll
  for (int k = 0; k < 2; ++k) {
    int i = k * 256 + tid, node = b * 512 + i;
    rp[i] = (node < n) ? rowptr[node] : 0;
    hf[i] = 0;
  }
  __syncthreads();
  int m = gcur[b];
  for (int i = tid; i < m; i += 256) {
    int ent = gbuf[(size_t)b * GCAP + i];
    int d = ent & 511, s = ent >> 9;
    csr[rp[d] + atomicAdd(&hf[d], 1)] = s;
  }
}

// ---- fp32 -> bf16 row conversion ------------------------------------------

__global__ __launch_bounds__(256) void k_tobf16(const float* __restrict__ in,
                                                short* __restrict__ ob, long long ng) {
  long long i = (long long)blockIdx.x * 256 + threadIdx.x;   // groups of 8 floats
  if (i >= ng) return;
  const float4* p = (const float4*)in + i * 2;
  float4 a = p[0], b = p[1];
  uint4 o;
  o.x = pack2(a.x, a.y); o.y = pack2(a.z, a.w);
  o.z = pack2(b.x, b.y); o.w = pack2(b.z, b.w);
  ((uint4*)ob)[i] = o;
}

// ---- weight prep: fp32 W[k][c] -> bf16 transposed WT[c][k] ----------------

__global__ __launch_bounds__(256) void k_wprep(const float* __restrict__ W0,
                                               const float* __restrict__ W1,
                                               const float* __restrict__ W2,
                                               const float* __restrict__ W3,
                                               short* __restrict__ WT) {
  const float* W = (blockIdx.y == 0) ? W0 : (blockIdx.y == 1) ? W1
                 : (blockIdx.y == 2) ? W2 : W3;
  short* o = WT + (size_t)blockIdx.y * WPANEL;
  int i = blockIdx.x * 256 + threadIdx.x;
  if (i < D * D) {
    int k = i >> 7, c = i & 127;
    o[c * WSTRIDE + k] = (short)f2bf(W[i]);
  }
}

// ---- bf16 mean aggregation: wave/node, 16-lane quarters --------------------

__global__ __launch_bounds__(256) void k_agg_bf(const short* __restrict__ hb,
                                                const int* __restrict__ rowptr,
                                                const int* __restrict__ csr,
                                                const float* __restrict__ inv_denom,
                                                short* __restrict__ agg, int n) {
  int gw = (int)((blockIdx.x * 256u + threadIdx.x) >> 6);
  if (gw >= n) return;
  int lane = threadIdx.x & 63;
  int q = lane >> 4, s16 = lane & 15;
  int beg = __builtin_amdgcn_readfirstlane(rowptr[gw]);
  int end = __builtin_amdgcn_readfirstlane(rowptr[gw + 1]);
  float acc[8];
#pragma unroll
  for (int k = 0; k < 8; ++k) acc[k] = 0.f;
  int e = beg + q;
  for (; e + 4 < end; e += 8) {   // 2 edges per quarter in flight
    int s0 = csr[e], s1 = csr[e + 4];
    uint4 v0 = ((const uint4*)(hb + (size_t)s0 * D))[s16];
    uint4 v1 = ((const uint4*)(hb + (size_t)s1 * D))[s16];
    acc[0] += __uint_as_float(v0.x << 16); acc[1] += __uint_as_float(v0.x & 0xffff0000u);
    acc[2] += __uint_as_float(v0.y << 16); acc[3] += __uint_as_float(v0.y & 0xffff0000u);
    acc[4] += __uint_as_float(v0.z << 16); acc[5] += __uint_as_float(v0.z & 0xffff0000u);
    acc[6] += __uint_as_float(v0.w << 16); acc[7] += __uint_as_float(v0.w & 0xffff0000u);
    acc[0] += __uint_as_float(v1.x << 16); acc[1] += __uint_as_float(v1.x & 0xffff0000u);
    acc[2] += __uint_as_float(v1.y << 16); acc[3] += __uint_as_float(v1.y & 0xffff0000u);
    acc[4] += __uint_as_float(v1.z << 16); acc[5] += __uint_as_float(v1.z & 0xffff0000u);
    acc[6] += __uint_as_float(v1.w << 16); acc[7] += __uint_as_float(v1.w & 0xffff0000u);
  }
  if (e < end) {
    int s0 = csr[e];
    uint4 v0 = ((const uint4*)(hb + (size_t)s0 * D))[s16];
    acc[0] += __uint_as_float(v0.x << 16); acc[1] += __uint_as_float(v0.x & 0xffff0000u);
    acc[2] += __uint_as_float(v0.y << 16); acc[3] += __uint_as_float(v0.y & 0xffff0000u);
    acc[4] += __uint_as_float(v0.z << 16); acc[5] += __uint_as_float(v0.z & 0xffff0000u);
    acc[6] += __uint_as_float(v0.w << 16); acc[7] += __uint_as_float(v0.w & 0xffff0000u);
  }
#pragma unroll
  for (int k = 0; k < 8; ++k) {
    acc[k] += __shfl_xor(acc[k], 16);
    acc[k] += __shfl_xor(acc[k], 32);
  }
  if (q == 0) {
    float iv = inv_denom[gw];
    uint4 o;
    o.x = pack2(acc[0] * iv, acc[1] * iv);
    o.y = pack2(acc[2] * iv, acc[3] * iv);
    o.z = pack2(acc[4] * iv, acc[5] * iv);
    o.w = pack2(acc[6] * iv, acc[7] * iv);
    ((uint4*)(agg + (size_t)gw * D))[s16] = o;
  }
}

// ---- fused layer GEMM (bf16 operands): out = relu(A@Wl + H@Wr + b) ---------
// OUTF=0: bf16 out; OUTF=1: fp32 out. Epilogue: per-wave 1280-B LDS slice,
// 80-B row stride; readback with lane l -> (row=l>>2, chunk=(l&3)*16B) so each
// store instruction covers 16 rows x full 64-B lines. LDS total 79872 B ->
// 2 blocks/CU.

template <int OUTF>
__global__ __launch_bounds__(512) void k_fgemm_bf(const short* __restrict__ A,
                                                  const short* __restrict__ H,
                                                  const short* __restrict__ WTl,
                                                  const short* __restrict__ WTr,
                                                  const float* __restrict__ bias,
                                                  void* __restrict__ outv, int n) {
  __shared__ short wl[WPANEL];
  __shared__ short wr[WPANEL];
  __shared__ int4 stageraw[640];   // 10240 B = 8 waves x 1280 B

  int tid = threadIdx.x;
  for (int i = tid; i < WPANEL / 8; i += 512) {
    ((int4*)wl)[i] = ((const int4*)WTl)[i];
    ((int4*)wr)[i] = ((const int4*)WTr)[i];
  }
  __syncthreads();

  int lane = tid & 63, wid = tid >> 6;
  int c = lane & 15, g = lane >> 4;
  float bv[8];
#pragma unroll
  for (int cc = 0; cc < 8; ++cc) bv[cc] = bias[cc * 16 + c];

  int ntile = (n + 15) >> 4;
  for (int tile = blockIdx.x * 8 + wid; tile < ntile; tile += gridDim.x * 8) {
    int r0 = tile * 16;
    int row = r0 + c;
    bool rok = row < n;
    f32x4 acc[8];
#pragma unroll
    for (int cc = 0; cc < 8; ++cc) acc[cc] = (f32x4){0.f, 0.f, 0.f, 0.f};

#pragma unroll
    for (int t = 0; t < 4; ++t) {
      short8v af = (short8v){0,0,0,0,0,0,0,0};
      short8v hf = (short8v){0,0,0,0,0,0,0,0};
      if (rok) {
        af = *(const short8v*)(A + (size_t)row * D + t * 32 + g * 8);
        hf = *(const short8v*)(H + (size_t)row * D + t * 32 + g * 8);
      }
      int kb = t * 32 + g * 8;
#pragma unroll
      for (int cc = 0; cc < 8; ++cc) {
        short8v bl = *(const short8v*)&wl[(cc * 16 + c) * WSTRIDE + kb];
        acc[cc] = __builtin_amdgcn_mfma_f32_16x16x32_bf16(af, bl, acc[cc], 0, 0, 0);
        short8v br = *(const short8v*)&wr[(cc * 16 + c) * WSTRIDE + kb];
        acc[cc] = __builtin_amdgcn_mfma_f32_16x16x32_bf16(hf, br, acc[cc], 0, 0, 0);
      }
    }

    // Epilogue. Same-wave LDS ops are in-order, so no barrier needed; the
    // WAR reuse of the slice across iterations is safe for the same reason.
    int rr = r0 + (lane >> 2);
    bool sok = rr < n;
    if (OUTF) {
      float* st = (float*)stageraw + wid * 320;          // 16 rows x 20 floats
#pragma unroll
      for (int cc = 0; cc < 8; ++cc) {
#pragma unroll
        for (int i = 0; i < 4; ++i) {
          float o = acc[cc][i] + bv[cc];
          st[(g * 4 + i) * 20 + c] = o > 0.f ? o : 0.f;
        }
        uint4 v = *(const uint4*)&st[(lane >> 2) * 20 + (lane & 3) * 4];
        if (sok)
          *(uint4*)((float*)outv + (size_t)rr * D + cc * 16 + (lane & 3) * 4) = v;
      }
    } else {
      short* st = (short*)stageraw + wid * 640;          // 16 rows x 40 shorts
#pragma unroll
      for (int cc2 = 0; cc2 < 4; ++cc2) {
#pragma unroll
        for (int half = 0; half < 2; ++half) {
          int cc = cc2 * 2 + half;
#pragma unroll
          for (int i = 0; i < 4; ++i) {
            float o = acc[cc][i] + bv[cc];
            st[(g * 4 + i) * 40 + half * 16 + c] = (short)f2bf(o > 0.f ? o : 0.f);
          }
        }
        uint4 v = *(const uint4*)&st[(lane >> 2) * 40 + (lane & 3) * 8];
        if (sok)
          *(uint4*)((short*)outv + (size_t)rr * D + cc2 * 32 + (lane & 3) * 8) = v;
      }
    }
  }
}

// ---- fp32 fallback kernels (used only if ws_size is too small) -------------

__global__ __launch_bounds__(256) void k_agg_f32(const float* __restrict__ h,
                                                 const int* __restrict__ rowptr,
                                                 const int* __restrict__ csr,
                                                 const float* __restrict__ inv_denom,
                                                 float* __restrict__ agg, int n) {
  int gw = (int)((blockIdx.x * 256u + threadIdx.x) >> 6);
  if (gw >= n) return;
  int lane = threadIdx.x & 63;
  int half = lane >> 5, sub = lane & 31;
  int beg = __builtin_amdgcn_readfirstlane(rowptr[gw]);
  int end = __builtin_amdgcn_readfirstlane(rowptr[gw + 1]);
  float sx0 = 0.f, sy0 = 0.f, sz0 = 0.f, sw0 = 0.f;
  float sx1 = 0.f, sy1 = 0.f, sz1 = 0.f, sw1 = 0.f;
  int e = beg;
  for (; e + 4 <= end; e += 4) {
    int i0 = csr[e + half];
    int i1 = csr[e + 2 + half];
    float4 v0 = ((const float4*)(h + (size_t)i0 * D))[sub];
    float4 v1 = ((const float4*)(h + (size_t)i1 * D))[sub];
    sx0 += v0.x; sy0 += v0.y; sz0 += v0.z; sw0 += v0.w;
    sx1 += v1.x; sy1 += v1.y; sz1 += v1.z; sw1 += v1.w;
  }
  if (e + 2 <= end) {
    int i0 = csr[e + half];
    float4 v0 = ((const float4*)(h + (size_t)i0 * D))[sub];
    sx0 += v0.x; sy0 += v0.y; sz0 += v0.z; sw0 += v0.w;
    e += 2;
  }
  if (e < end) {
    int i0 = csr[e];
    float4 v0 = ((const float4*)(h + (size_t)i0 * D))[sub];
    if (half == 0) { sx0 += v0.x; sy0 += v0.y; sz0 += v0.z; sw0 += v0.w; }
  }
  float sx = sx0 + sx1, sy = sy0 + sy1, sz = sz0 + sz1, sw = sw0 + sw1;
  sx += __shfl_xor(sx, 32); sy += __shfl_xor(sy, 32);
  sz += __shfl_xor(sz, 32); sw += __shfl_xor(sw, 32);
  if (half == 0) {
    float iv = inv_denom[gw];
    float4 r; r.x = sx * iv; r.y = sy * iv; r.z = sz * iv; r.w = sw * iv;
    ((float4*)(agg + (size_t)gw * D))[sub] = r;
  }
}

__global__ __launch_bounds__(512) void k_fgemm_f32(const float* A, const float* H,
                                                   const short* __restrict__ WTl,
                                                   const short* __restrict__ WTr,
                                                   const float* __restrict__ bias,
                                                   float* out, int n) {
  __shared__ short wl[WPANEL];
  __shared__ short wr[WPANEL];
  int tid = threadIdx.x;
  for (int i = tid; i < WPANEL / 8; i += 512) {
    ((int4*)wl)[i] = ((const int4*)WTl)[i];
    ((int4*)wr)[i] = ((const int4*)WTr)[i];
  }
  __syncthreads();
  int lane = tid & 63, wid = tid >> 6;
  int c = lane & 15, g = lane >> 4;
  float bv[8];
#pragma unroll
  for (int cc = 0; cc < 8; ++cc) bv[cc] = bias[cc * 16 + c];
  int ntile = (n + 15) >> 4;
  for (int tile = blockIdx.x * 8 + wid; tile < ntile; tile += gridDim.x * 8) {
    int r0 = tile * 16;
    int row = r0 + c;
    bool rok = row < n;
    f32x4 acc[8];
#pragma unroll
    for (int cc = 0; cc < 8; ++cc) acc[cc] = (f32x4){0.f, 0.f, 0.f, 0.f};
#pragma unroll
    for (int t = 0; t < 4; ++t) {
      short8v af = (short8v){0,0,0,0,0,0,0,0};
      short8v hf = (short8v){0,0,0,0,0,0,0,0};
      if (rok) {
        const float4* pa = (const float4*)(A + (size_t)row * D + t * 32 + g * 8);
        float4 a0 = pa[0], a1 = pa[1];
        const float4* ph = (const float4*)(H + (size_t)row * D + t * 32 + g * 8);
        float4 h0 = ph[0], h1 = ph[1];
        af[0] = (short)f2bf(a0.x); af[1] = (short)f2bf(a0.y); af[2] = (short)f2bf(a0.z); af[3] = (short)f2bf(a0.w);
        af[4] = (short)f2bf(a1.x); af[5] = (short)f2bf(a1.y); af[6] = (short)f2bf(a1.z); af[7] = (short)f2bf(a1.w);
        hf[0] = (short)f2bf(h0.x); hf[1] = (short)f2bf(h0.y); hf[2] = (short)f2bf(h0.z); hf[3] = (short)f2bf(h0.w);
        hf[4] = (short)f2bf(h1.x); hf[5] = (short)f2bf(h1.y); hf[6] = (short)f2bf(h1.z); hf[7] = (short)f2bf(h1.w);
      }
      int kb = t * 32 + g * 8;
#pragma unroll
      for (int cc = 0; cc < 8; ++cc) {
        short8v bl = *(const short8v*)&wl[(cc * 16 + c) * WSTRIDE + kb];
        acc[cc] = __builtin_amdgcn_mfma_f32_16x16x32_bf16(af, bl, acc[cc], 0, 0, 0);
        short8v br = *(const short8v*)&wr[(cc * 16 + c) * WSTRIDE + kb];
        acc[cc] = __builtin_amdgcn_mfma_f32_16x16x32_bf16(hf, br, acc[cc], 0, 0, 0);
      }
    }
#pragma unroll
    for (int cc = 0; cc < 8; ++cc) {
#pragma unroll
      for (int i = 0; i < 4; ++i) {
        int rr = r0 + g * 4 + i;
        if (rr < n) {
          float o = acc[cc][i] + bv[cc];
          out[(size_t)rr * D + cc * 16 + c] = o > 0.f ? o : 0.f;
        }
      }
    }
  }
}

// ---- launch ----------------------------------------------------------------

extern "C" void kernel_launch(void* const* d_in, const int* in_sizes, int n_in,
                              void* d_out, int out_size, void* d_ws, size_t ws_size,
                              hipStream_t stream) {
  const float* x   = (const float*)d_in[0];
  const int*   ei  = (const int*)d_in[1];
  const float* Wl0 = (const float*)d_in[2];
  const float* Wr0 = (const float*)d_in[3];
  const float* b0  = (const float*)d_in[4];
  const float* Wl1 = (const float*)d_in[5];
  const float* Wr1 = (const float*)d_in[6];
  const float* b1  = (const float*)d_in[7];
  const int N = in_sizes[0] / D;
  const int E = in_sizes[1] / 2;
  float* out = (float*)d_out;

  size_t NP = ((size_t)N + 64) & ~(size_t)63;
  size_t EP = ((size_t)E + 63) & ~(size_t)63;
  const int NBUCK = (N + 511) >> 9;

  int* W = (int*)d_ws;
  size_t off = 0;
  int*   rowptr = W + off; off += NP;
  int*   cnt    = W + off; off += NP;
  float* inv    = (float*)(W + off); off += NP;
  int*   bsum   = W + off; off += 1024;
  int*   gcur   = W + off; off += 256;
  int*   csr    = W + off; off += EP;
  short* wt     = (short*)(W + off); off += (size_t)4 * WPANEL / 2;
  size_t base = off;
  short* aggb = (short*)(W + off); off += NP * 64;
  short* xb   = (short*)(W + off); off += NP * 64;
  short* h1b  = (short*)(W + off); off += NP * 64;
  size_t need_new = off * 4;
  float* aggf = (float*)(W + base);                 // fallback fp32 agg buffer
  bool use_bf = ws_size >= need_new;
  int* gbuf = use_bf ? (int*)xb : (int*)aggf;       // overlay: consumed pre-agg

  hipMemsetAsync(gcur, 0, 256 * sizeof(int), stream);

  int NB = (N + 1023) / 1024;
  k_bin<<<(E + 2047) / 2048, 256, 0, stream>>>(ei, E, gcur, gbuf);
  k_hist<<<NBUCK, 256, 0, stream>>>(gcur, gbuf, cnt, N);
  k_scan1<<<NB, 1024, 0, stream>>>(cnt, N, rowptr, inv, bsum);
  k_scan2<<<1, 64, 0, stream>>>(bsum, NB, rowptr, N);
  k_scan3<<<NB, 1024, 0, stream>>>(rowptr, bsum, N);
  k_place<<<NBUCK, 256, 0, stream>>>(gcur, gbuf, rowptr, csr, N);

  dim3 wgrid((D * D + 255) / 256, 4);
  k_wprep<<<wgrid, 256, 0, stream>>>(Wl0, Wr0, Wl1, Wr1, wt);

  int agrid = (N + 3) / 4;

  if (use_bf) {
    long long ng = (long long)N * (D / 8);
    k_tobf16<<<(int)((ng + 255) / 256), 256, 0, stream>>>(x, xb, ng);
    // layer 0
    k_agg_bf<<<agrid, 256, 0, stream>>>(xb, rowptr, csr, inv, aggb, N);
    k_fgemm_bf<0><<<512, 512, 0, stream>>>(aggb, xb, wt, wt + WPANEL, b0, h1b, N);
    // layer 1
    k_agg_bf<<<agrid, 256, 0, stream>>>(h1b, rowptr, csr, inv, aggb, N);
    k_fgemm_bf<1><<<512, 512, 0, stream>>>(aggb, h1b, wt + 2 * WPANEL, wt + 3 * WPANEL, b1, out, N);
  } else {
    // fp32 fallback (proven footprint)
    k_agg_f32<<<agrid, 256, 0, stream>>>(x, rowptr, csr, inv, aggf, N);
    k_fgemm_f32<<<512, 512, 0, stream>>>(aggf, x, wt, wt + WPANEL, b0, out, N);
    k_agg_f32<<<agrid, 256, 0, stream>>>(out, rowptr, csr, inv, aggf, N);
    k_fgemm_f32<<<512, 512, 0, stream>>>(aggf, out, wt + 2 * WPANEL, wt + 3 * WPANEL, b1, out, N);
  }
}

// Round 7
// 263.407 us; speedup vs baseline: 1.4190x; 1.2286x over previous
//
#include <hip/hip_runtime.h>
#include <hip/hip_bf16.h>

// GraphSAGE backbone: 2x SAGEConv(mean), N=100000, E=1600000, D=128, fp32 in/out.
// CSR build via 2-pass bucket binning, then per layer:
//   agg = mean gather (bf16 rows, fp32 accum, 4-deep MLP);
//   out = relu(agg@Wl + h@Wr + b) fused bf16 MFMA GEMM with NO LDS:
//   weights pre-swizzled to fragment-major layout, streamed from L2.

#define D 128
#define WSTRIDE 136            // 128 + 8 bf16 pad (fallback path only)
#define WPANEL (D * WSTRIDE)   // shorts per fallback weight panel
#define GCAP 12288             // per-bucket capacity (mean ~8166)

typedef __attribute__((ext_vector_type(8))) short short8v;
typedef __attribute__((ext_vector_type(4))) float f32x4;

__device__ inline unsigned short f2bf(float f) {   // fp32 -> bf16 RNE
  unsigned u = __float_as_uint(f);
  return (unsigned short)((u + 0x7FFFu + ((u >> 16) & 1u)) >> 16);
}
__device__ inline unsigned pack2(float lo, float hi) {
  return (unsigned)f2bf(lo) | ((unsigned)f2bf(hi) << 16);
}

// ---- pass A: bin edges by dst>>9 into gbuf[b*GCAP + cursor] ---------------

__global__ __launch_bounds__(256) void k_bin(const int* __restrict__ ei, int E,
                                             int* __restrict__ gcur,
                                             int* __restrict__ gbuf) {
  __shared__ int hcnt[256], hbase[256], hfill[256];
  int tid = threadIdx.x;
  hcnt[tid] = 0;
  __syncthreads();
  int ent[8], bk[8];
#pragma unroll
  for (int it = 0; it < 8; ++it) {
    int e = blockIdx.x * 2048 + it * 256 + tid;
    if (e < E) {
      int s = ei[e], d = ei[E + e];
      bk[it] = d >> 9;
      ent[it] = (s << 9) | (d & 511);
      atomicAdd(&hcnt[bk[it]], 1);
    } else bk[it] = -1;
  }
  __syncthreads();
  int c = hcnt[tid];
  hbase[tid] = c ? atomicAdd(&gcur[tid], c) : 0;
  hfill[tid] = 0;
  __syncthreads();
#pragma unroll
  for (int it = 0; it < 8; ++it) {
    if (bk[it] >= 0) {
      int slot = atomicAdd(&hfill[bk[it]], 1);
      gbuf[(size_t)bk[it] * GCAP + hbase[bk[it]] + slot] = ent[it];
    }
  }
}

// ---- pass B1: per-bucket degree histogram -> cnt (coalesced) ---------------

__global__ __launch_bounds__(256) void k_hist(const int* __restrict__ gcur,
                                              const int* __restrict__ gbuf,
                                              int* __restrict__ cnt, int n) {
  __shared__ int hc[512];
  int b = blockIdx.x, tid = threadIdx.x;
  hc[tid] = 0; hc[tid + 256] = 0;
  __syncthreads();
  int m = gcur[b];
  for (int i = tid; i < m; i += 256)
    atomicAdd(&hc[gbuf[(size_t)b * GCAP + i] & 511], 1);
  __syncthreads();
#pragma unroll
  for (int k = 0; k < 2; ++k) {
    int i = k * 256 + tid, node = b * 512 + i;
    if (node < n) cnt[node] = hc[i];
  }
}

// ---- hierarchical exclusive scan: cnt -> rowptr, plus inv_denom ------------

__global__ __launch_bounds__(1024) void k_scan1(const int* __restrict__ cnt, int n,
                                                int* __restrict__ rowptr,
                                                float* __restrict__ inv_denom,
                                                int* __restrict__ bsum) {
  __shared__ int wsum[16];
  int tid = threadIdx.x, lane = tid & 63, wid = tid >> 6;
  int i = blockIdx.x * 1024 + tid;
  int v = (i < n) ? cnt[i] : 0;
  int x = v;
#pragma unroll
  for (int off = 1; off < 64; off <<= 1) {
    int t = __shfl_up(x, (unsigned)off);
    if (lane >= off) x += t;
  }
  if (lane == 63) wsum[wid] = x;
  __syncthreads();
  if (tid < 16) {
    int w = wsum[tid], y = w;
#pragma unroll
    for (int off = 1; off < 16; off <<= 1) {
      int t = __shfl_up(y, (unsigned)off);
      if (tid >= off) y += t;
    }
    wsum[tid] = y - w;   // exclusive
  }
  __syncthreads();
  if (i < n) {
    rowptr[i] = wsum[wid] + x - v;
    inv_denom[i] = 1.0f / (float)((v > 1) ? v : 1);
  }
  if (tid == 1023) bsum[blockIdx.x] = wsum[15] + x;
}

__global__ __launch_bounds__(64) void k_scan2(int* __restrict__ bsum, int nb,
                                              int* __restrict__ rowptr, int n) {
  int lane = threadIdx.x;
  int v0 = (lane < nb) ? bsum[lane] : 0;
  int v1 = (64 + lane < nb) ? bsum[64 + lane] : 0;
  int x = v0;
#pragma unroll
  for (int off = 1; off < 64; off <<= 1) {
    int t = __shfl_up(x, (unsigned)off);
    if (lane >= off) x += t;
  }
  int tot0 = __shfl(x, 63);
  int y = v1;
#pragma unroll
  for (int off = 1; off < 64; off <<= 1) {
    int t = __shfl_up(y, (unsigned)off);
    if (lane >= off) y += t;
  }
  if (lane < nb) bsum[lane] = x - v0;
  if (64 + lane < nb) bsum[64 + lane] = tot0 + (y - v1);
  if (lane == 63) rowptr[n] = tot0 + y;
}

__global__ __launch_bounds__(1024) void k_scan3(int* __restrict__ rowptr,
                                                const int* __restrict__ bsum, int n) {
  int i = blockIdx.x * 1024 + threadIdx.x;
  if (i < n) rowptr[i] += bsum[blockIdx.x];
}

// ---- pass B2: place entries into csr (one bucket = one block) --------------

__global__ __launch_bounds__(256) void k_place(const int* __restrict__ gcur,
                                               const int* __restrict__ gbuf,
                                               const int* __restrict__ rowptr,
                                               int* __restrict__ csr, int n) {
  __shared__ int rp[512], hf[512];
  int b = blockIdx.x, tid = threadIdx.x;
#pragma unroll
  for (int k = 0; k < 2; ++k) {
    int i = k * 256 + tid, node = b * 512 + i;
    rp[i] = (node < n) ? rowptr[node] : 0;
    hf[i] = 0;
  }
  __syncthreads();
  int m = gcur[b];
  for (int i = tid; i < m; i += 256) {
    int ent = gbuf[(size_t)b * GCAP + i];
    int d = ent & 511, s = ent >> 9;
    csr[rp[d] + atomicAdd(&hf[d], 1)] = s;
  }
}

// ---- fp32 -> bf16 row conversion ------------------------------------------

__global__ __launch_bounds__(256) void k_tobf16(const float* __restrict__ in,
                                                short* __restrict__ ob, long long ng) {
  long long i = (long long)blockIdx.x * 256 + threadIdx.x;   // groups of 8 floats
  if (i >= ng) return;
  const float4* p = (const float4*)in + i * 2;
  float4 a = p[0], b = p[1];
  uint4 o;
  o.x = pack2(a.x, a.y); o.y = pack2(a.z, a.w);
  o.z = pack2(b.x, b.y); o.w = pack2(b.z, b.w);
  ((uint4*)ob)[i] = o;
}

// ---- weight prep (fragment-major): WF[((t*8+cc)*64+l)*8+j] =
//        bf16( W[t*32 + (l>>4)*8 + j][cc*16 + (l&15)] )  -------------------

__global__ __launch_bounds__(256) void k_wprep_frag(const float* __restrict__ W0,
                                                    const float* __restrict__ W1,
                                                    const float* __restrict__ W2,
                                                    const float* __restrict__ W3,
                                                    short* __restrict__ WF) {
  const float* W = (blockIdx.y == 0) ? W0 : (blockIdx.y == 1) ? W1
                 : (blockIdx.y == 2) ? W2 : W3;
  short* o = WF + (size_t)blockIdx.y * (D * D);
  int i = blockIdx.x * 256 + threadIdx.x;
  if (i < D * D) {
    int j = i & 7, l = (i >> 3) & 63, cc = (i >> 9) & 7, t = i >> 12;
    int k = t * 32 + (l >> 4) * 8 + j;
    int c = cc * 16 + (l & 15);
    o[i] = (short)f2bf(W[k * D + c]);
  }
}

// ---- weight prep (old padded-transpose layout, fallback path only) ---------

__global__ __launch_bounds__(256) void k_wprep(const float* __restrict__ W0,
                                               const float* __restrict__ W1,
                                               const float* __restrict__ W2,
                                               const float* __restrict__ W3,
                                               short* __restrict__ WT) {
  const float* W = (blockIdx.y == 0) ? W0 : (blockIdx.y == 1) ? W1
                 : (blockIdx.y == 2) ? W2 : W3;
  short* o = WT + (size_t)blockIdx.y * WPANEL;
  int i = blockIdx.x * 256 + threadIdx.x;
  if (i < D * D) {
    int k = i >> 7, c = i & 127;
    o[c * WSTRIDE + k] = (short)f2bf(W[i]);
  }
}

// ---- bf16 mean aggregation: wave/node, 16-lane quarters, 4-deep MLP --------

__global__ __launch_bounds__(256) void k_agg_bf(const short* __restrict__ hb,
                                                const int* __restrict__ rowptr,
                                                const int* __restrict__ csr,
                                                const float* __restrict__ inv_denom,
                                                short* __restrict__ agg, int n) {
  int gw = (int)((blockIdx.x * 256u + threadIdx.x) >> 6);
  if (gw >= n) return;
  int lane = threadIdx.x & 63;
  int q = lane >> 4, s16 = lane & 15;
  int beg = __builtin_amdgcn_readfirstlane(rowptr[gw]);
  int end = __builtin_amdgcn_readfirstlane(rowptr[gw + 1]);
  float acc[8];
#pragma unroll
  for (int k = 0; k < 8; ++k) acc[k] = 0.f;
  auto addrow = [&](uint4 v) {
    acc[0] += __uint_as_float(v.x << 16); acc[1] += __uint_as_float(v.x & 0xffff0000u);
    acc[2] += __uint_as_float(v.y << 16); acc[3] += __uint_as_float(v.y & 0xffff0000u);
    acc[4] += __uint_as_float(v.z << 16); acc[5] += __uint_as_float(v.z & 0xffff0000u);
    acc[6] += __uint_as_float(v.w << 16); acc[7] += __uint_as_float(v.w & 0xffff0000u);
  };
  int e = beg + q;
  for (; e + 12 < end; e += 16) {   // 4 edges in flight per quarter
    int s0 = csr[e], s1 = csr[e + 4], s2 = csr[e + 8], s3 = csr[e + 12];
    uint4 v0 = ((const uint4*)(hb + (size_t)s0 * D))[s16];
    uint4 v1 = ((const uint4*)(hb + (size_t)s1 * D))[s16];
    uint4 v2 = ((const uint4*)(hb + (size_t)s2 * D))[s16];
    uint4 v3 = ((const uint4*)(hb + (size_t)s3 * D))[s16];
    addrow(v0); addrow(v1); addrow(v2); addrow(v3);
  }
  for (; e + 4 < end; e += 8) {     // 2-deep tail
    int s0 = csr[e], s1 = csr[e + 4];
    uint4 v0 = ((const uint4*)(hb + (size_t)s0 * D))[s16];
    uint4 v1 = ((const uint4*)(hb + (size_t)s1 * D))[s16];
    addrow(v0); addrow(v1);
  }
  if (e < end) {
    int s0 = csr[e];
    uint4 v0 = ((const uint4*)(hb + (size_t)s0 * D))[s16];
    addrow(v0);
  }
#pragma unroll
  for (int k = 0; k < 8; ++k) {
    acc[k] += __shfl_xor(acc[k], 16);
    acc[k] += __shfl_xor(acc[k], 32);
  }
  if (q == 0) {
    float iv = inv_denom[gw];
    uint4 o;
    o.x = pack2(acc[0] * iv, acc[1] * iv);
    o.y = pack2(acc[2] * iv, acc[3] * iv);
    o.z = pack2(acc[4] * iv, acc[5] * iv);
    o.w = pack2(acc[6] * iv, acc[7] * iv);
    ((uint4*)(agg + (size_t)gw * D))[s16] = o;
  }
}

// ---- fused layer GEMM, NO LDS: out = relu(A@Wl + H@Wr + b) -----------------
// Wave owns a 32-row tile (two 16-row halves share each B-fragment).
// B-fragments loaded fragment-major from global (L2-resident, coalesced).
// OUTF=0: bf16 out; OUTF=1: fp32 out.

template <int OUTF>
__global__ __launch_bounds__(256) void k_fgemm_bf(const short* __restrict__ A,
                                                  const short* __restrict__ H,
                                                  const short* __restrict__ WFl,
                                                  const short* __restrict__ WFr,
                                                  const float* __restrict__ bias,
                                                  void* __restrict__ outv, int n) {
  int tid = threadIdx.x;
  int lane = tid & 63, w4 = tid >> 6;
  int nt = (n + 31) >> 5;
  int wtile = blockIdx.x * 4 + w4;
  if (wtile >= nt) return;
  int c = lane & 15, g = lane >> 4;
  int r0 = wtile * 32;
  int row0 = r0 + c, row1 = r0 + 16 + c;
  bool ok0 = row0 < n, ok1 = row1 < n;

  float bv[8];
#pragma unroll
  for (int cc = 0; cc < 8; ++cc) bv[cc] = bias[cc * 16 + c];

  const short8v* Fl = (const short8v*)WFl;
  const short8v* Fr = (const short8v*)WFr;

  f32x4 acc0[8], acc1[8];
#pragma unroll
  for (int cc = 0; cc < 8; ++cc) {
    acc0[cc] = (f32x4){0.f, 0.f, 0.f, 0.f};
    acc1[cc] = (f32x4){0.f, 0.f, 0.f, 0.f};
  }

#pragma unroll
  for (int t = 0; t < 4; ++t) {
    short8v a0 = (short8v){0,0,0,0,0,0,0,0}, h0 = a0, a1 = a0, h1 = a0;
    int kb = t * 32 + g * 8;
    if (ok0) {
      a0 = *(const short8v*)(A + (size_t)row0 * D + kb);
      h0 = *(const short8v*)(H + (size_t)row0 * D + kb);
    }
    if (ok1) {
      a1 = *(const short8v*)(A + (size_t)row1 * D + kb);
      h1 = *(const short8v*)(H + (size_t)row1 * D + kb);
    }
#pragma unroll
    for (int cc = 0; cc < 8; ++cc) {
      short8v bl = Fl[(t * 8 + cc) * 64 + lane];
      short8v br = Fr[(t * 8 + cc) * 64 + lane];
      acc0[cc] = __builtin_amdgcn_mfma_f32_16x16x32_bf16(a0, bl, acc0[cc], 0, 0, 0);
      acc0[cc] = __builtin_amdgcn_mfma_f32_16x16x32_bf16(h0, br, acc0[cc], 0, 0, 0);
      acc1[cc] = __builtin_amdgcn_mfma_f32_16x16x32_bf16(a1, bl, acc1[cc], 0, 0, 0);
      acc1[cc] = __builtin_amdgcn_mfma_f32_16x16x32_bf16(h1, br, acc1[cc], 0, 0, 0);
    }
  }

#pragma unroll
  for (int cc = 0; cc < 8; ++cc) {
#pragma unroll
    for (int i = 0; i < 4; ++i) {
      int rr0 = r0 + g * 4 + i;
      int rr1 = rr0 + 16;
      float o0 = acc0[cc][i] + bv[cc];
      float o1 = acc1[cc][i] + bv[cc];
      o0 = o0 > 0.f ? o0 : 0.f;
      o1 = o1 > 0.f ? o1 : 0.f;
      if (OUTF) {
        if (rr0 < n) ((float*)outv)[(size_t)rr0 * D + cc * 16 + c] = o0;
        if (rr1 < n) ((float*)outv)[(size_t)rr1 * D + cc * 16 + c] = o1;
      } else {
        if (rr0 < n) ((short*)outv)[(size_t)rr0 * D + cc * 16 + c] = (short)f2bf(o0);
        if (rr1 < n) ((short*)outv)[(size_t)rr1 * D + cc * 16 + c] = (short)f2bf(o1);
      }
    }
  }
}

// ---- fp32 fallback kernels (used only if ws_size is too small) -------------

__global__ __launch_bounds__(256) void k_agg_f32(const float* __restrict__ h,
                                                 const int* __restrict__ rowptr,
                                                 const int* __restrict__ csr,
                                                 const float* __restrict__ inv_denom,
                                                 float* __restrict__ agg, int n) {
  int gw = (int)((blockIdx.x * 256u + threadIdx.x) >> 6);
  if (gw >= n) return;
  int lane = threadIdx.x & 63;
  int half = lane >> 5, sub = lane & 31;
  int beg = __builtin_amdgcn_readfirstlane(rowptr[gw]);
  int end = __builtin_amdgcn_readfirstlane(rowptr[gw + 1]);
  float sx0 = 0.f, sy0 = 0.f, sz0 = 0.f, sw0 = 0.f;
  float sx1 = 0.f, sy1 = 0.f, sz1 = 0.f, sw1 = 0.f;
  int e = beg;
  for (; e + 4 <= end; e += 4) {
    int i0 = csr[e + half];
    int i1 = csr[e + 2 + half];
    float4 v0 = ((const float4*)(h + (size_t)i0 * D))[sub];
    float4 v1 = ((const float4*)(h + (size_t)i1 * D))[sub];
    sx0 += v0.x; sy0 += v0.y; sz0 += v0.z; sw0 += v0.w;
    sx1 += v1.x; sy1 += v1.y; sz1 += v1.z; sw1 += v1.w;
  }
  if (e + 2 <= end) {
    int i0 = csr[e + half];
    float4 v0 = ((const float4*)(h + (size_t)i0 * D))[sub];
    sx0 += v0.x; sy0 += v0.y; sz0 += v0.z; sw0 += v0.w;
    e += 2;
  }
  if (e < end) {
    int i0 = csr[e];
    float4 v0 = ((const float4*)(h + (size_t)i0 * D))[sub];
    if (half == 0) { sx0 += v0.x; sy0 += v0.y; sz0 += v0.z; sw0 += v0.w; }
  }
  float sx = sx0 + sx1, sy = sy0 + sy1, sz = sz0 + sz1, sw = sw0 + sw1;
  sx += __shfl_xor(sx, 32); sy += __shfl_xor(sy, 32);
  sz += __shfl_xor(sz, 32); sw += __shfl_xor(sw, 32);
  if (half == 0) {
    float iv = inv_denom[gw];
    float4 r; r.x = sx * iv; r.y = sy * iv; r.z = sz * iv; r.w = sw * iv;
    ((float4*)(agg + (size_t)gw * D))[sub] = r;
  }
}

__global__ __launch_bounds__(512) void k_fgemm_f32(const float* A, const float* H,
                                                   const short* __restrict__ WTl,
                                                   const short* __restrict__ WTr,
                                                   const float* __restrict__ bias,
                                                   float* out, int n) {
  __shared__ short wl[WPANEL];
  __shared__ short wr[WPANEL];
  int tid = threadIdx.x;
  for (int i = tid; i < WPANEL / 8; i += 512) {
    ((int4*)wl)[i] = ((const int4*)WTl)[i];
    ((int4*)wr)[i] = ((const int4*)WTr)[i];
  }
  __syncthreads();
  int lane = tid & 63, wid = tid >> 6;
  int c = lane & 15, g = lane >> 4;
  float bv[8];
#pragma unroll
  for (int cc = 0; cc < 8; ++cc) bv[cc] = bias[cc * 16 + c];
  int ntile = (n + 15) >> 4;
  for (int tile = blockIdx.x * 8 + wid; tile < ntile; tile += gridDim.x * 8) {
    int r0 = tile * 16;
    int row = r0 + c;
    bool rok = row < n;
    f32x4 acc[8];
#pragma unroll
    for (int cc = 0; cc < 8; ++cc) acc[cc] = (f32x4){0.f, 0.f, 0.f, 0.f};
#pragma unroll
    for (int t = 0; t < 4; ++t) {
      short8v af = (short8v){0,0,0,0,0,0,0,0};
      short8v hf = (short8v){0,0,0,0,0,0,0,0};
      if (rok) {
        const float4* pa = (const float4*)(A + (size_t)row * D + t * 32 + g * 8);
        float4 a0 = pa[0], a1 = pa[1];
        const float4* ph = (const float4*)(H + (size_t)row * D + t * 32 + g * 8);
        float4 h0 = ph[0], h1 = ph[1];
        af[0] = (short)f2bf(a0.x); af[1] = (short)f2bf(a0.y); af[2] = (short)f2bf(a0.z); af[3] = (short)f2bf(a0.w);
        af[4] = (short)f2bf(a1.x); af[5] = (short)f2bf(a1.y); af[6] = (short)f2bf(a1.z); af[7] = (short)f2bf(a1.w);
        hf[0] = (short)f2bf(h0.x); hf[1] = (short)f2bf(h0.y); hf[2] = (short)f2bf(h0.z); hf[3] = (short)f2bf(h0.w);
        hf[4] = (short)f2bf(h1.x); hf[5] = (short)f2bf(h1.y); hf[6] = (short)f2bf(h1.z); hf[7] = (short)f2bf(h1.w);
      }
      int kb = t * 32 + g * 8;
#pragma unroll
      for (int cc = 0; cc < 8; ++cc) {
        short8v bl = *(const short8v*)&wl[(cc * 16 + c) * WSTRIDE + kb];
        acc[cc] = __builtin_amdgcn_mfma_f32_16x16x32_bf16(af, bl, acc[cc], 0, 0, 0);
        short8v br = *(const short8v*)&wr[(cc * 16 + c) * WSTRIDE + kb];
        acc[cc] = __builtin_amdgcn_mfma_f32_16x16x32_bf16(hf, br, acc[cc], 0, 0, 0);
      }
    }
#pragma unroll
    for (int cc = 0; cc < 8; ++cc) {
#pragma unroll
      for (int i = 0; i < 4; ++i) {
        int rr = r0 + g * 4 + i;
        if (rr < n) {
          float o = acc[cc][i] + bv[cc];
          out[(size_t)rr * D + cc * 16 + c] = o > 0.f ? o : 0.f;
        }
      }
    }
  }
}

// ---- launch ----------------------------------------------------------------

extern "C" void kernel_launch(void* const* d_in, const int* in_sizes, int n_in,
                              void* d_out, int out_size, void* d_ws, size_t ws_size,
                              hipStream_t stream) {
  const float* x   = (const float*)d_in[0];
  const int*   ei  = (const int*)d_in[1];
  const float* Wl0 = (const float*)d_in[2];
  const float* Wr0 = (const float*)d_in[3];
  const float* b0  = (const float*)d_in[4];
  const float* Wl1 = (const float*)d_in[5];
  const float* Wr1 = (const float*)d_in[6];
  const float* b1  = (const float*)d_in[7];
  const int N = in_sizes[0] / D;
  const int E = in_sizes[1] / 2;
  float* out = (float*)d_out;

  size_t NP = ((size_t)N + 64) & ~(size_t)63;
  size_t EP = ((size_t)E + 63) & ~(size_t)63;
  const int NBUCK = (N + 511) >> 9;

  int* W = (int*)d_ws;
  size_t off = 0;
  int*   rowptr = W + off; off += NP;
  int*   cnt    = W + off; off += NP;
  float* inv    = (float*)(W + off); off += NP;
  int*   bsum   = W + off; off += 1024;
  int*   gcur   = W + off; off += 256;
  int*   csr    = W + off; off += EP;
  short* wt     = (short*)(W + off); off += (size_t)4 * WPANEL / 2;   // fallback layout
  short* wf     = (short*)(W + off); off += (size_t)4 * (D * D) / 2;  // frag layout
  size_t base = off;
  short* aggb = (short*)(W + off); off += NP * 64;
  short* xb   = (short*)(W + off); off += NP * 64;
  short* h1b  = (short*)(W + off); off += NP * 64;
  size_t need_new = off * 4;
  float* aggf = (float*)(W + base);                 // fallback fp32 agg buffer
  bool use_bf = ws_size >= need_new;
  int* gbuf = use_bf ? (int*)xb : (int*)aggf;       // overlay: consumed pre-agg

  hipMemsetAsync(gcur, 0, 256 * sizeof(int), stream);

  int NB = (N + 1023) / 1024;
  k_bin<<<(E + 2047) / 2048, 256, 0, stream>>>(ei, E, gcur, gbuf);
  k_hist<<<NBUCK, 256, 0, stream>>>(gcur, gbuf, cnt, N);
  k_scan1<<<NB, 1024, 0, stream>>>(cnt, N, rowptr, inv, bsum);
  k_scan2<<<1, 64, 0, stream>>>(bsum, NB, rowptr, N);
  k_scan3<<<NB, 1024, 0, stream>>>(rowptr, bsum, N);
  k_place<<<NBUCK, 256, 0, stream>>>(gcur, gbuf, rowptr, csr, N);

  int agrid = (N + 3) / 4;
  dim3 wgrid((D * D + 255) / 256, 4);

  if (use_bf) {
    k_wprep_frag<<<wgrid, 256, 0, stream>>>(Wl0, Wr0, Wl1, Wr1, wf);
    long long ng = (long long)N * (D / 8);
    k_tobf16<<<(int)((ng + 255) / 256), 256, 0, stream>>>(x, xb, ng);
    int nt32 = (N + 31) >> 5;
    int ggrid = (nt32 + 3) / 4;
    // layer 0
    k_agg_bf<<<agrid, 256, 0, stream>>>(xb, rowptr, csr, inv, aggb, N);
    k_fgemm_bf<0><<<ggrid, 256, 0, stream>>>(aggb, xb, wf, wf + D * D, b0, h1b, N);
    // layer 1
    k_agg_bf<<<agrid, 256, 0, stream>>>(h1b, rowptr, csr, inv, aggb, N);
    k_fgemm_bf<1><<<ggrid, 256, 0, stream>>>(aggb, h1b, wf + 2 * D * D, wf + 3 * D * D, b1, out, N);
  } else {
    // fp32 fallback (proven footprint)
    k_wprep<<<wgrid, 256, 0, stream>>>(Wl0, Wr0, Wl1, Wr1, wt);
    k_agg_f32<<<agrid, 256, 0, stream>>>(x, rowptr, csr, inv, aggf, N);
    k_fgemm_f32<<<512, 512, 0, stream>>>(aggf, x, wt, wt + WPANEL, b0, out, N);
    k_agg_f32<<<agrid, 256, 0, stream>>>(out, rowptr, csr, inv, aggf, N);
    k_fgemm_f32<<<512, 512, 0, stream>>>(aggf, out, wt + 2 * WPANEL, wt + 3 * WPANEL, b1, out, N);
  }
}